// Round 2
// baseline (113.397 us; speedup 1.0000x reference)
//
#include <hip/hip_runtime.h>

// out[b, j] = s1[b] + s0[b]*conj(w[j]) + bias   (complex64)
//   s1[b] = sum_i x[b,i] * w[i]   (complex)
//   s0[b] = sum_i x[b,i]          (real)
// real part = s1r + s0*wr[j] + br ; imag part = s1i - s0*wi[j] + bi
//
// The harness's d_out may hold either B*N float32 (real part only — the
// expected npz size indicates a complex->float32 astype, which drops imag)
// or 2*B*N float32 (interleaved complex). Decide from out_size at launch.

constexpr int BLOCK = 256;

template <bool COMPLEX_OUT>
__global__ __launch_bounds__(BLOCK) void pelinear_fused(
    const float* __restrict__ x,
    const float* __restrict__ wr,
    const float* __restrict__ wi,
    const float* __restrict__ bre,
    const float* __restrict__ bim,
    float* __restrict__ out,
    int ncols)
{
    const int row = blockIdx.x;
    const float* xrow = x + (size_t)row * ncols;

    // ---- Phase 1: row reduction (s0, s1r, s1i), float4-vectorized ----
    float s0 = 0.f, s1r = 0.f, s1i = 0.f;
    const int iters = ncols / (BLOCK * 4);   // 8 for N=8192
    for (int it = 0; it < iters; ++it) {
        const int i = (it * BLOCK + threadIdx.x) * 4;
        const float4 xv  = *reinterpret_cast<const float4*>(xrow + i);
        const float4 wrv = *reinterpret_cast<const float4*>(wr + i);
        s0  += (xv.x + xv.y) + (xv.z + xv.w);
        s1r += xv.x * wrv.x + xv.y * wrv.y + xv.z * wrv.z + xv.w * wrv.w;
        if (COMPLEX_OUT) {
            const float4 wiv = *reinterpret_cast<const float4*>(wi + i);
            s1i += xv.x * wiv.x + xv.y * wiv.y + xv.z * wiv.z + xv.w * wiv.w;
        }
    }

    // wave (64-lane) reduce, then cross-wave via LDS
    #pragma unroll
    for (int off = 32; off > 0; off >>= 1) {
        s0  += __shfl_down(s0, off);
        s1r += __shfl_down(s1r, off);
        if (COMPLEX_OUT) s1i += __shfl_down(s1i, off);
    }
    __shared__ float red[3][BLOCK / 64];
    const int wave = threadIdx.x >> 6;
    const int lane = threadIdx.x & 63;
    if (lane == 0) {
        red[0][wave] = s0;
        red[1][wave] = s1r;
        red[2][wave] = s1i;
    }
    __syncthreads();
    const float rs0 = (red[0][0] + red[0][1]) + (red[0][2] + red[0][3]);
    const float cr  = (red[1][0] + red[1][1]) + (red[1][2] + red[1][3]) + bre[0];

    if (COMPLEX_OUT) {
        const float ci = (red[2][0] + red[2][1]) + (red[2][2] + red[2][3]) + bim[0];
        float* orow = out + (size_t)row * ncols * 2;
        for (int it = 0; it < iters; ++it) {
            const int j = (it * BLOCK + threadIdx.x) * 4;
            const float4 wrv = *reinterpret_cast<const float4*>(wr + j);
            const float4 wiv = *reinterpret_cast<const float4*>(wi + j);
            float4 o0, o1;
            o0.x = cr + rs0 * wrv.x;  o0.y = ci - rs0 * wiv.x;
            o0.z = cr + rs0 * wrv.y;  o0.w = ci - rs0 * wiv.y;
            o1.x = cr + rs0 * wrv.z;  o1.y = ci - rs0 * wiv.z;
            o1.z = cr + rs0 * wrv.w;  o1.w = ci - rs0 * wiv.w;
            *reinterpret_cast<float4*>(orow + 2 * (size_t)j)     = o0;
            *reinterpret_cast<float4*>(orow + 2 * (size_t)j + 4) = o1;
        }
    } else {
        // Real part only: out[b,j] = cr + rs0 * wr[j]
        float* orow = out + (size_t)row * ncols;
        for (int it = 0; it < iters; ++it) {
            const int j = (it * BLOCK + threadIdx.x) * 4;
            const float4 wrv = *reinterpret_cast<const float4*>(wr + j);
            float4 o;
            o.x = cr + rs0 * wrv.x;
            o.y = cr + rs0 * wrv.y;
            o.z = cr + rs0 * wrv.z;
            o.w = cr + rs0 * wrv.w;
            *reinterpret_cast<float4*>(orow + j) = o;
        }
    }
}

extern "C" void kernel_launch(void* const* d_in, const int* in_sizes, int n_in,
                              void* d_out, int out_size, void* d_ws, size_t ws_size,
                              hipStream_t stream) {
    const float* x  = (const float*)d_in[0];
    const float* wr = (const float*)d_in[1];
    const float* wi = (const float*)d_in[2];
    const float* br = (const float*)d_in[3];
    const float* bi = (const float*)d_in[4];
    float* out = (float*)d_out;

    const int ncols = in_sizes[1];              // N = 8192
    const int nrows = in_sizes[0] / ncols;      // B = 8192

    if ((long long)out_size >= 2LL * nrows * ncols) {
        pelinear_fused<true><<<nrows, BLOCK, 0, stream>>>(x, wr, wi, br, bi, out, ncols);
    } else {
        pelinear_fused<false><<<nrows, BLOCK, 0, stream>>>(x, wr, wi, br, bi, out, ncols);
    }
}